// Round 1
// baseline (688.896 us; speedup 1.0000x reference)
//
#include <hip/hip_runtime.h>

// WordAttention: mix = softmax(relu(c@W^T+b) @ relu(q@W^T+b)^T) @ q
// B=32, CL=2048, QL=512, DIM=512, fp32 in/out, fp16 MFMA compute (fp32 accum).

#define BATCH 32
#define CL    2048
#define QL    512
#define DIM   512
#define CT    32      // c-rows per workgroup

typedef _Float16 f16x8 __attribute__((ext_vector_type(8)));
typedef _Float16 f16x4 __attribute__((ext_vector_type(4)));
typedef float    f32x4 __attribute__((ext_vector_type(4)));

#define LDA 520   // padded fp16 row for 32-row A tiles (stride 1040 B -> 2-way banks, free)
#define LDB 40    // padded fp16 row for 512x32 B chunks (stride 80 B -> 2-way banks, free)

// ---------------- prep: W fp32 -> fp16 ----------------
__global__ void k_prep_w(const float* __restrict__ W, _Float16* __restrict__ Wh) {
    int i = (blockIdx.x * 256 + threadIdx.x) * 4;   // 256 blocks x 256 thr x 4 = 262144
    float4 v = *(const float4*)(W + i);
    f16x4 h = {(_Float16)v.x, (_Float16)v.y, (_Float16)v.z, (_Float16)v.w};
    *(f16x4*)(Wh + i) = h;
}

// ---------------- prep: qT[b][d][j] = fp16(q[b][j][d]) ----------------
__global__ void k_prep_qt(const float* __restrict__ q, _Float16* __restrict__ qT) {
    __shared__ _Float16 t[64][65];
    int b  = blockIdx.x;            // 32
    int jt = blockIdx.y;            // QL/64 = 8
    int dt = blockIdx.z;            // DIM/64 = 8
    const float* src = q + ((size_t)b * QL + jt * 64) * DIM + dt * 64;
    int r0 = threadIdx.x >> 6;      // 0..3
    int cc = threadIdx.x & 63;
#pragma unroll
    for (int p = 0; p < 16; ++p) {
        int r = r0 + p * 4;
        t[r][cc] = (_Float16)src[(size_t)r * DIM + cc];
    }
    __syncthreads();
    _Float16* dst = qT + ((size_t)b * DIM + dt * 64) * QL + jt * 64;
#pragma unroll
    for (int p = 0; p < 16; ++p) {
        int r = r0 + p * 4;
        dst[(size_t)r * QL + cc] = t[cc][r];   // qT[b][d0+r][j0+cc] = q[b][j0+cc][d0+r]
    }
}

// ---------------- q_feat = relu(q @ Wh^T + bias), fp16 out ----------------
__global__ __launch_bounds__(256)
void k_qfeat(const float* __restrict__ q, const _Float16* __restrict__ Wh,
             const float* __restrict__ bias, _Float16* __restrict__ qf) {
    __shared__ __align__(16) _Float16 At[CT][LDA];
    __shared__ __align__(16) _Float16 Bt[512][LDB];
    int b   = blockIdx.x >> 4;            // 32 batches
    int j0  = (blockIdx.x & 15) * CT;     // 16 j-tiles of 32
    int tid = threadIdx.x;
    int w = tid >> 6, lane = tid & 63;
    int col = lane & 15, quad = lane >> 4;

    // stage A tile (q rows, fp32 -> fp16)
    const float4* src = (const float4*)(q + ((size_t)b * QL + j0) * DIM);
#pragma unroll
    for (int s = 0; s < 16; ++s) {
        int seg = tid + s * 256;          // 4096 float4 segments
        int r = seg >> 7, c4 = seg & 127;
        float4 v = src[r * 128 + c4];
        f16x4 h = {(_Float16)v.x, (_Float16)v.y, (_Float16)v.z, (_Float16)v.w};
        *(f16x4*)&At[r][c4 * 4] = h;
    }
    __syncthreads();

    f32x4 acc[2][8];
#pragma unroll
    for (int it = 0; it < 2; ++it)
#pragma unroll
        for (int jt = 0; jt < 8; ++jt) acc[it][jt] = (f32x4){0.f, 0.f, 0.f, 0.f};

    int ebase = w * 128;
    for (int kc = 0; kc < 16; ++kc) {
        int k0 = kc * 32;
#pragma unroll
        for (int s = 0; s < 8; ++s) {     // stage Wh[0..512)[k0..k0+32)
            int seg = tid + s * 256;
            int e = seg >> 2, cp = seg & 3;
            *(uint4*)&Bt[e][cp * 8] = *(const uint4*)(Wh + (size_t)e * DIM + k0 + cp * 8);
        }
        __syncthreads();
        f16x8 a0 = *(const f16x8*)&At[col][k0 + quad * 8];
        f16x8 a1 = *(const f16x8*)&At[16 + col][k0 + quad * 8];
#pragma unroll
        for (int jt = 0; jt < 8; ++jt) {
            f16x8 bf = *(const f16x8*)&Bt[ebase + jt * 16 + col][quad * 8];
            acc[0][jt] = __builtin_amdgcn_mfma_f32_16x16x32_f16(a0, bf, acc[0][jt], 0, 0, 0);
            acc[1][jt] = __builtin_amdgcn_mfma_f32_16x16x32_f16(a1, bf, acc[1][jt], 0, 0, 0);
        }
        __syncthreads();
    }
    // epilogue: bias + relu -> qf (fp16)
#pragma unroll
    for (int jt = 0; jt < 8; ++jt) {
        int e = ebase + jt * 16 + col;
        float bv = bias[e];
#pragma unroll
        for (int it = 0; it < 2; ++it)
#pragma unroll
            for (int r = 0; r < 4; ++r) {
                int i = it * 16 + quad * 4 + r;
                float v = acc[it][jt][r] + bv;
                v = fmaxf(v, 0.f);
                qf[((size_t)b * QL + j0 + i) * DIM + e] = (_Float16)v;
            }
    }
}

// ---------------- fused main: c-proj -> scores -> softmax -> mix ----------------
__global__ __launch_bounds__(256)
void k_main(const float* __restrict__ c, const _Float16* __restrict__ Wh,
            const float* __restrict__ bias, const _Float16* __restrict__ qf,
            const _Float16* __restrict__ qT, float* __restrict__ out) {
    __shared__ __align__(16) _Float16 At[CT][LDA];   // c tile; later reused as attn tile
    __shared__ __align__(16) _Float16 Bt[512][LDB];  // B-operand k-chunk (W / qf / qT rows)
    __shared__ __align__(16) _Float16 Cf[CT][LDA];   // c_feat tile
    __shared__ float redmax[4][32];
    __shared__ float redsum[4][32];

    int b   = blockIdx.x >> 6;            // 32 batches
    int c0  = (blockIdx.x & 63) * CT;     // 64 c-tiles of 32
    int tid = threadIdx.x;
    int w = tid >> 6, lane = tid & 63;
    int col = lane & 15, quad = lane >> 4;
    int obase = w * 128;                  // this wave's output-column range (e / j / d)

    // ---- stage c tile (fp32 -> fp16) ----
    const float4* csrc = (const float4*)(c + ((size_t)b * CL + c0) * DIM);
#pragma unroll
    for (int s = 0; s < 16; ++s) {
        int seg = tid + s * 256;
        int r = seg >> 7, c4 = seg & 127;
        float4 v = csrc[r * 128 + c4];
        f16x4 h = {(_Float16)v.x, (_Float16)v.y, (_Float16)v.z, (_Float16)v.w};
        *(f16x4*)&At[r][c4 * 4] = h;
    }
    __syncthreads();

    f32x4 acc[2][8];
#pragma unroll
    for (int it = 0; it < 2; ++it)
#pragma unroll
        for (int jt = 0; jt < 8; ++jt) acc[it][jt] = (f32x4){0.f, 0.f, 0.f, 0.f};

    // ---- phase 1: Cf = relu(c @ Wh^T + bias) ----
    for (int kc = 0; kc < 16; ++kc) {
        int k0 = kc * 32;
#pragma unroll
        for (int s = 0; s < 8; ++s) {
            int seg = tid + s * 256;
            int e = seg >> 2, cp = seg & 3;
            *(uint4*)&Bt[e][cp * 8] = *(const uint4*)(Wh + (size_t)e * DIM + k0 + cp * 8);
        }
        __syncthreads();
        f16x8 a0 = *(const f16x8*)&At[col][k0 + quad * 8];
        f16x8 a1 = *(const f16x8*)&At[16 + col][k0 + quad * 8];
#pragma unroll
        for (int jt = 0; jt < 8; ++jt) {
            f16x8 bf = *(const f16x8*)&Bt[obase + jt * 16 + col][quad * 8];
            acc[0][jt] = __builtin_amdgcn_mfma_f32_16x16x32_f16(a0, bf, acc[0][jt], 0, 0, 0);
            acc[1][jt] = __builtin_amdgcn_mfma_f32_16x16x32_f16(a1, bf, acc[1][jt], 0, 0, 0);
        }
        __syncthreads();
    }
#pragma unroll
    for (int jt = 0; jt < 8; ++jt) {
        int e = obase + jt * 16 + col;
        float bv = bias[e];
#pragma unroll
        for (int it = 0; it < 2; ++it)
#pragma unroll
            for (int r = 0; r < 4; ++r) {
                float v = acc[it][jt][r] + bv;
                Cf[it * 16 + quad * 4 + r][e] = (_Float16)fmaxf(v, 0.f);
            }
    }
    __syncthreads();

    // ---- phase 2: S = Cf @ qf[b]^T  (this wave: j in [obase, obase+128)) ----
#pragma unroll
    for (int it = 0; it < 2; ++it)
#pragma unroll
        for (int jt = 0; jt < 8; ++jt) acc[it][jt] = (f32x4){0.f, 0.f, 0.f, 0.f};
    const _Float16* qfb = qf + (size_t)b * QL * DIM;
    for (int kc = 0; kc < 16; ++kc) {
        int k0 = kc * 32;
#pragma unroll
        for (int s = 0; s < 8; ++s) {
            int seg = tid + s * 256;
            int j = seg >> 2, cp = seg & 3;
            *(uint4*)&Bt[j][cp * 8] = *(const uint4*)(qfb + (size_t)j * DIM + k0 + cp * 8);
        }
        __syncthreads();
        f16x8 a0 = *(const f16x8*)&Cf[col][k0 + quad * 8];
        f16x8 a1 = *(const f16x8*)&Cf[16 + col][k0 + quad * 8];
#pragma unroll
        for (int jt = 0; jt < 8; ++jt) {
            f16x8 bf = *(const f16x8*)&Bt[obase + jt * 16 + col][quad * 8];
            acc[0][jt] = __builtin_amdgcn_mfma_f32_16x16x32_f16(a0, bf, acc[0][jt], 0, 0, 0);
            acc[1][jt] = __builtin_amdgcn_mfma_f32_16x16x32_f16(a1, bf, acc[1][jt], 0, 0, 0);
        }
        __syncthreads();
    }

    // ---- phase 3: softmax over j (rows = c-rows), attn -> At (fp16) ----
    float sm[2][4];
#pragma unroll
    for (int it = 0; it < 2; ++it)
#pragma unroll
        for (int r = 0; r < 4; ++r) {
            float m = -1e30f;
#pragma unroll
            for (int jt = 0; jt < 8; ++jt) m = fmaxf(m, acc[it][jt][r]);
            m = fmaxf(m, __shfl_xor(m, 1));
            m = fmaxf(m, __shfl_xor(m, 2));
            m = fmaxf(m, __shfl_xor(m, 4));
            m = fmaxf(m, __shfl_xor(m, 8));
            sm[it][r] = m;   // wave-partial row max
        }
    if (col == 0) {
#pragma unroll
        for (int it = 0; it < 2; ++it)
#pragma unroll
            for (int r = 0; r < 4; ++r) redmax[w][it * 16 + quad * 4 + r] = sm[it][r];
    }
    __syncthreads();
#pragma unroll
    for (int it = 0; it < 2; ++it)
#pragma unroll
        for (int r = 0; r < 4; ++r) {
            int i = it * 16 + quad * 4 + r;
            float gm = fmaxf(fmaxf(redmax[0][i], redmax[1][i]),
                             fmaxf(redmax[2][i], redmax[3][i]));
            float s = 0.f;
#pragma unroll
            for (int jt = 0; jt < 8; ++jt) {
                float e = __expf(acc[it][jt][r] - gm);
                acc[it][jt][r] = e;
                s += e;
            }
            s += __shfl_xor(s, 1);
            s += __shfl_xor(s, 2);
            s += __shfl_xor(s, 4);
            s += __shfl_xor(s, 8);
            sm[it][r] = s;   // wave-partial row sum
        }
    if (col == 0) {
#pragma unroll
        for (int it = 0; it < 2; ++it)
#pragma unroll
            for (int r = 0; r < 4; ++r) redsum[w][it * 16 + quad * 4 + r] = sm[it][r];
    }
    __syncthreads();
#pragma unroll
    for (int it = 0; it < 2; ++it)
#pragma unroll
        for (int r = 0; r < 4; ++r) {
            int i = it * 16 + quad * 4 + r;
            float tot = redsum[0][i] + redsum[1][i] + redsum[2][i] + redsum[3][i];
            float inv = 1.f / tot;
#pragma unroll
            for (int jt = 0; jt < 8; ++jt)
                At[i][obase + jt * 16 + col] = (_Float16)(acc[it][jt][r] * inv);
        }
    // (attn writes covered by the barrier after phase-4's first staging)

    // ---- phase 4: mix = attn @ q[b]  (B operand = qT rows d, k=j contiguous) ----
#pragma unroll
    for (int it = 0; it < 2; ++it)
#pragma unroll
        for (int jt = 0; jt < 8; ++jt) acc[it][jt] = (f32x4){0.f, 0.f, 0.f, 0.f};
    const _Float16* qTb = qT + (size_t)b * DIM * QL;
    for (int kc = 0; kc < 16; ++kc) {
        int k0 = kc * 32;
#pragma unroll
        for (int s = 0; s < 8; ++s) {
            int seg = tid + s * 256;
            int d = seg >> 2, cp = seg & 3;
            *(uint4*)&Bt[d][cp * 8] = *(const uint4*)(qTb + (size_t)d * QL + k0 + cp * 8);
        }
        __syncthreads();
        f16x8 a0 = *(const f16x8*)&At[col][k0 + quad * 8];
        f16x8 a1 = *(const f16x8*)&At[16 + col][k0 + quad * 8];
#pragma unroll
        for (int jt = 0; jt < 8; ++jt) {
            f16x8 bf = *(const f16x8*)&Bt[obase + jt * 16 + col][quad * 8];
            acc[0][jt] = __builtin_amdgcn_mfma_f32_16x16x32_f16(a0, bf, acc[0][jt], 0, 0, 0);
            acc[1][jt] = __builtin_amdgcn_mfma_f32_16x16x32_f16(a1, bf, acc[1][jt], 0, 0, 0);
        }
        __syncthreads();
    }
    // ---- epilogue: out[b][c0+i][d] fp32 ----
#pragma unroll
    for (int dt = 0; dt < 8; ++dt) {
        int d = obase + dt * 16 + col;
#pragma unroll
        for (int it = 0; it < 2; ++it)
#pragma unroll
            for (int r = 0; r < 4; ++r) {
                int i = it * 16 + quad * 4 + r;
                out[((size_t)b * CL + c0 + i) * DIM + d] = acc[it][dt][r];
            }
    }
}

extern "C" void kernel_launch(void* const* d_in, const int* in_sizes, int n_in,
                              void* d_out, int out_size, void* d_ws, size_t ws_size,
                              hipStream_t stream) {
    const float* c    = (const float*)d_in[0];
    const float* q    = (const float*)d_in[1];
    const float* W    = (const float*)d_in[2];
    const float* bias = (const float*)d_in[3];
    float* out = (float*)d_out;

    // ws layout: Wh fp16 (512 KB) | qf fp16 (16 MB) | qT fp16 (16 MB)  = 34,078,720 B
    char* ws = (char*)d_ws;
    _Float16* Wh = (_Float16*)ws;
    _Float16* qf = (_Float16*)(ws + 524288);
    _Float16* qT = (_Float16*)(ws + 524288 + 16777216);

    k_prep_w<<<256, 256, 0, stream>>>(W, Wh);
    k_prep_qt<<<dim3(BATCH, QL / 64, DIM / 64), 256, 0, stream>>>(q, qT);
    k_qfeat<<<BATCH * (QL / CT), 256, 0, stream>>>(q, Wh, bias, qf);
    k_main<<<BATCH * (CL / CT), 256, 0, stream>>>(c, Wh, bias, qf, qT, out);
}

// Round 2
// 615.404 us; speedup vs baseline: 1.1194x; 1.1194x over previous
//
#include <hip/hip_runtime.h>

// WordAttention: mix = softmax(relu(c@W^T+b) @ relu(q@W^T+b)^T) @ q
// B=32, CL=2048, QL=512, DIM=512, fp32 in/out, fp16 MFMA compute (fp32 accum).
// R2: cf precomputed by 128x128-tile GEMM; attention kernel has barrier-free
// K-loops (A from LDS, B fragments gathered directly from L2-resident global).

#define BATCH 32
#define CL    2048
#define QL    512
#define DIM   512
#define CT    32      // c-rows per attention workgroup

typedef _Float16 f16x8 __attribute__((ext_vector_type(8)));
typedef _Float16 f16x4 __attribute__((ext_vector_type(4)));
typedef float    f32x4 __attribute__((ext_vector_type(4)));

#define LDA 520   // attn kernel A-tile row (halfs): 1040 B stride, 16B-aligned
#define LDK 40    // proj kernel k-chunk row (halfs): 80 B stride, 16B-aligned

// ---------------- prep: W fp32 -> fp16 ----------------
__global__ void k_prep_w(const float* __restrict__ W, _Float16* __restrict__ Wh) {
    int i = (blockIdx.x * 256 + threadIdx.x) * 4;
    float4 v = *(const float4*)(W + i);
    f16x4 h = {(_Float16)v.x, (_Float16)v.y, (_Float16)v.z, (_Float16)v.w};
    *(f16x4*)(Wh + i) = h;
}

// ---------------- prep: qT[b][d][j] = fp16(q[b][j][d]) ----------------
__global__ void k_prep_qt(const float* __restrict__ q, _Float16* __restrict__ qT) {
    __shared__ _Float16 t[64][65];
    int b  = blockIdx.x;
    int jt = blockIdx.y;            // QL/64
    int dt = blockIdx.z;            // DIM/64
    const float* src = q + ((size_t)b * QL + jt * 64) * DIM + dt * 64;
    int r0 = threadIdx.x >> 6;
    int cc = threadIdx.x & 63;
#pragma unroll
    for (int p = 0; p < 16; ++p) {
        int r = r0 + p * 4;
        t[r][cc] = (_Float16)src[(size_t)r * DIM + cc];
    }
    __syncthreads();
    _Float16* dst = qT + ((size_t)b * DIM + dt * 64) * QL + jt * 64;
#pragma unroll
    for (int p = 0; p < 16; ++p) {
        int r = r0 + p * 4;
        dst[(size_t)r * QL + cc] = t[cc][r];
    }
}

// ---------------- Y = relu(X @ Wh^T + bias), fp16 out; 128x128 tiles ----------------
__global__ __launch_bounds__(256)
void k_proj(const float* __restrict__ X, const _Float16* __restrict__ Wh,
            const float* __restrict__ bias, _Float16* __restrict__ Y) {
    __shared__ __align__(16) _Float16 Ah[128][LDK];
    __shared__ __align__(16) _Float16 Bh[128][LDK];
    int m0 = blockIdx.x * 128;
    int n0 = blockIdx.y * 128;
    int tid = threadIdx.x;
    int w = tid >> 6, lane = tid & 63;
    int col = lane & 15, quad = lane >> 4;
    int wm = (w >> 1) * 64, wn = (w & 1) * 64;

    f32x4 acc[4][4];
#pragma unroll
    for (int it = 0; it < 4; ++it)
#pragma unroll
        for (int jt = 0; jt < 4; ++jt) acc[it][jt] = (f32x4){0.f, 0.f, 0.f, 0.f};

    for (int kc = 0; kc < 16; ++kc) {
        int k0 = kc * 32;
        // stage A: 128 rows x 32 floats -> fp16 (1024 float4 segs, 4/thread)
#pragma unroll
        for (int p = 0; p < 4; ++p) {
            int s = tid + p * 256;
            int r = s >> 3, c4 = s & 7;
            float4 v = *(const float4*)(X + (size_t)(m0 + r) * DIM + k0 + c4 * 4);
            f16x4 h = {(_Float16)v.x, (_Float16)v.y, (_Float16)v.z, (_Float16)v.w};
            *(f16x4*)&Ah[r][c4 * 4] = h;
        }
        // stage B: 128 rows x 32 halfs (512 uint4 segs, 2/thread)
#pragma unroll
        for (int p = 0; p < 2; ++p) {
            int s = tid + p * 256;
            int r = s >> 2, cc = s & 3;
            *(uint4*)&Bh[r][cc * 8] = *(const uint4*)(Wh + (size_t)(n0 + r) * DIM + k0 + cc * 8);
        }
        __syncthreads();
        f16x8 af[4], bf[4];
#pragma unroll
        for (int it = 0; it < 4; ++it) af[it] = *(const f16x8*)&Ah[wm + it * 16 + col][quad * 8];
#pragma unroll
        for (int jt = 0; jt < 4; ++jt) bf[jt] = *(const f16x8*)&Bh[wn + jt * 16 + col][quad * 8];
#pragma unroll
        for (int it = 0; it < 4; ++it)
#pragma unroll
            for (int jt = 0; jt < 4; ++jt)
                acc[it][jt] = __builtin_amdgcn_mfma_f32_16x16x32_f16(af[it], bf[jt], acc[it][jt], 0, 0, 0);
        __syncthreads();
    }
    // epilogue: bias + relu -> fp16
#pragma unroll
    for (int jt = 0; jt < 4; ++jt) {
        int e = n0 + wn + jt * 16 + col;
        float bv = bias[e];
#pragma unroll
        for (int it = 0; it < 4; ++it)
#pragma unroll
            for (int r = 0; r < 4; ++r) {
                int row = m0 + wm + it * 16 + quad * 4 + r;
                Y[(size_t)row * DIM + e] = (_Float16)fmaxf(acc[it][jt][r] + bv, 0.f);
            }
    }
}

// ---------------- fused attention: scores -> softmax -> mix ----------------
__global__ __launch_bounds__(256)
void k_attn(const _Float16* __restrict__ cf, const _Float16* __restrict__ qf,
            const _Float16* __restrict__ qT, float* __restrict__ out) {
    __shared__ __align__(16) _Float16 At[CT][LDA];   // cf tile, then attn tile
    __shared__ float redmax[4][32];
    __shared__ float redsum[4][32];

    int b   = blockIdx.x >> 6;            // 32 batches
    int c0  = (blockIdx.x & 63) * CT;     // 64 c-tiles of 32
    int tid = threadIdx.x;
    int w = tid >> 6, lane = tid & 63;
    int col = lane & 15, quad = lane >> 4;
    int obase = w * 128;                  // this wave's j / d column range

    // ---- stage cf tile (fp16, 2048 uint4 segs, 8/thread) ----
    const _Float16* cfb = cf + ((size_t)b * CL + c0) * DIM;
#pragma unroll
    for (int p = 0; p < 8; ++p) {
        int s = tid + p * 256;
        int r = s >> 6, cc = s & 63;
        *(uint4*)&At[r][cc * 8] = *(const uint4*)(cfb + (size_t)r * DIM + cc * 8);
    }
    __syncthreads();

    // ---- phase 2: S = cf_tile @ qf[b]^T ; B fragments direct from global ----
    f32x4 acc[2][8];
#pragma unroll
    for (int it = 0; it < 2; ++it)
#pragma unroll
        for (int jt = 0; jt < 8; ++jt) acc[it][jt] = (f32x4){0.f, 0.f, 0.f, 0.f};
    const _Float16* qfb = qf + (size_t)b * QL * DIM;
#pragma unroll 4
    for (int kc = 0; kc < 16; ++kc) {
        int k0 = kc * 32;
        f16x8 bf[8];
#pragma unroll
        for (int jt = 0; jt < 8; ++jt)
            bf[jt] = *(const f16x8*)(qfb + (size_t)(obase + jt * 16 + col) * DIM + k0 + quad * 8);
        f16x8 a0 = *(const f16x8*)&At[col][k0 + quad * 8];
        f16x8 a1 = *(const f16x8*)&At[16 + col][k0 + quad * 8];
#pragma unroll
        for (int jt = 0; jt < 8; ++jt) {
            acc[0][jt] = __builtin_amdgcn_mfma_f32_16x16x32_f16(a0, bf[jt], acc[0][jt], 0, 0, 0);
            acc[1][jt] = __builtin_amdgcn_mfma_f32_16x16x32_f16(a1, bf[jt], acc[1][jt], 0, 0, 0);
        }
    }

    // ---- phase 3: softmax over j ----
    float sm[2][4];
#pragma unroll
    for (int it = 0; it < 2; ++it)
#pragma unroll
        for (int r = 0; r < 4; ++r) {
            float m = -1e30f;
#pragma unroll
            for (int jt = 0; jt < 8; ++jt) m = fmaxf(m, acc[it][jt][r]);
            m = fmaxf(m, __shfl_xor(m, 1));
            m = fmaxf(m, __shfl_xor(m, 2));
            m = fmaxf(m, __shfl_xor(m, 4));
            m = fmaxf(m, __shfl_xor(m, 8));
            sm[it][r] = m;
        }
    if (col == 0) {
#pragma unroll
        for (int it = 0; it < 2; ++it)
#pragma unroll
            for (int r = 0; r < 4; ++r) redmax[w][it * 16 + quad * 4 + r] = sm[it][r];
    }
    __syncthreads();   // also guarantees all At(cf) reads are done
#pragma unroll
    for (int it = 0; it < 2; ++it)
#pragma unroll
        for (int r = 0; r < 4; ++r) {
            int i = it * 16 + quad * 4 + r;
            float gm = fmaxf(fmaxf(redmax[0][i], redmax[1][i]),
                             fmaxf(redmax[2][i], redmax[3][i]));
            float s = 0.f;
#pragma unroll
            for (int jt = 0; jt < 8; ++jt) {
                float e = __expf(acc[it][jt][r] - gm);
                acc[it][jt][r] = e;
                s += e;
            }
            s += __shfl_xor(s, 1);
            s += __shfl_xor(s, 2);
            s += __shfl_xor(s, 4);
            s += __shfl_xor(s, 8);
            sm[it][r] = s;
        }
    if (col == 0) {
#pragma unroll
        for (int it = 0; it < 2; ++it)
#pragma unroll
            for (int r = 0; r < 4; ++r) redsum[w][it * 16 + quad * 4 + r] = sm[it][r];
    }
    __syncthreads();
#pragma unroll
    for (int it = 0; it < 2; ++it)
#pragma unroll
        for (int r = 0; r < 4; ++r) {
            int i = it * 16 + quad * 4 + r;
            float tot = redsum[0][i] + redsum[1][i] + redsum[2][i] + redsum[3][i];
            float inv = 1.f / tot;
#pragma unroll
            for (int jt = 0; jt < 8; ++jt)
                At[i][obase + jt * 16 + col] = (_Float16)(acc[it][jt][r] * inv);
        }
    __syncthreads();   // attn tile visible to all waves

    // ---- phase 4: mix = attn @ q[b] ; B = qT fragments direct from global ----
#pragma unroll
    for (int it = 0; it < 2; ++it)
#pragma unroll
        for (int jt = 0; jt < 8; ++jt) acc[it][jt] = (f32x4){0.f, 0.f, 0.f, 0.f};
    const _Float16* qTb = qT + (size_t)b * DIM * QL;
#pragma unroll 4
    for (int kc = 0; kc < 16; ++kc) {
        int k0 = kc * 32;
        f16x8 bf[8];
#pragma unroll
        for (int dt = 0; dt < 8; ++dt)
            bf[dt] = *(const f16x8*)(qTb + (size_t)(obase + dt * 16 + col) * QL + k0 + quad * 8);
        f16x8 a0 = *(const f16x8*)&At[col][k0 + quad * 8];
        f16x8 a1 = *(const f16x8*)&At[16 + col][k0 + quad * 8];
#pragma unroll
        for (int dt = 0; dt < 8; ++dt) {
            acc[0][dt] = __builtin_amdgcn_mfma_f32_16x16x32_f16(a0, bf[dt], acc[0][dt], 0, 0, 0);
            acc[1][dt] = __builtin_amdgcn_mfma_f32_16x16x32_f16(a1, bf[dt], acc[1][dt], 0, 0, 0);
        }
    }
    // ---- epilogue: out fp32 ----
#pragma unroll
    for (int dt = 0; dt < 8; ++dt) {
        int d = obase + dt * 16 + col;
#pragma unroll
        for (int it = 0; it < 2; ++it)
#pragma unroll
            for (int r = 0; r < 4; ++r) {
                int i = it * 16 + quad * 4 + r;
                out[((size_t)b * CL + c0 + i) * DIM + d] = acc[it][dt][r];
            }
    }
}

extern "C" void kernel_launch(void* const* d_in, const int* in_sizes, int n_in,
                              void* d_out, int out_size, void* d_ws, size_t ws_size,
                              hipStream_t stream) {
    const float* c    = (const float*)d_in[0];
    const float* q    = (const float*)d_in[1];
    const float* W    = (const float*)d_in[2];
    const float* bias = (const float*)d_in[3];
    float* out = (float*)d_out;

    // ws: Wh 512K | qf 16M | qT 16M | cf 64M  = ~96.5 MB
    char* ws = (char*)d_ws;
    _Float16* Wh = (_Float16*)ws;
    _Float16* qf = (_Float16*)(ws + 524288);
    _Float16* qT = (_Float16*)(ws + 524288 + 16777216);
    _Float16* cf = (_Float16*)(ws + 524288 + 16777216 + 16777216);

    k_prep_w<<<256, 256, 0, stream>>>(W, Wh);
    k_prep_qt<<<dim3(BATCH, QL / 64, DIM / 64), 256, 0, stream>>>(q, qT);
    k_proj<<<dim3((BATCH * QL) / 128, DIM / 128), 256, 0, stream>>>(q, Wh, bias, qf);
    k_proj<<<dim3((BATCH * CL) / 128, DIM / 128), 256, 0, stream>>>(c, Wh, bias, cf);
    k_attn<<<BATCH * (CL / CT), 256, 0, stream>>>(cf, qf, qT, out);
}

// Round 3
// 537.731 us; speedup vs baseline: 1.2811x; 1.1444x over previous
//
#include <hip/hip_runtime.h>

// WordAttention: mix = softmax(relu(c@W^T+b) @ relu(q@W^T+b)^T) @ q
// B=32, CL=2048, QL=512, DIM=512, fp32 in/out, fp16 MFMA compute (fp32 accum).
// R3: all MFMA B-operands pre-shuffled into fragment-major layout
// [rowtile][kstep][lane][8] so every fragment load is base + lane*16B
// (contiguous 1KB/instr, no 16-row gather). k_proj keeps only A in LDS.

#define BATCH 32
#define CL    2048
#define QL    512
#define DIM   512
#define CT    32      // c-rows per attention workgroup

typedef _Float16 f16x8 __attribute__((ext_vector_type(8)));
typedef _Float16 f16x4 __attribute__((ext_vector_type(4)));
typedef float    f32x4 __attribute__((ext_vector_type(4)));

#define LDA 520   // attn A-tile row (halfs)
#define LDP 72    // proj A-stage row (halfs): bank offset 36 dwords -> 2-way, free

// ---- shuffle row-major fp16 [M][512] into fragment-major [M/16][16][64][8] ----
// group g: rt=g>>10, kstep=(g>>6)&15, lane=g&63 ; element j of group =
// in[rt*16 + (lane&15)][kstep*32 + (lane>>4)*8 + j]
__global__ void k_shuf_f16(const _Float16* __restrict__ in, _Float16* __restrict__ out) {
    size_t g = (size_t)blockIdx.x * 256 + threadIdx.x;
    int rt = (int)(g >> 10), ks = (int)(g >> 6) & 15, l = (int)g & 63;
    const _Float16* src = in + ((size_t)(rt * 16 + (l & 15))) * 512 + ks * 32 + (l >> 4) * 8;
    *(uint4*)(out + g * 8) = *(const uint4*)src;
}

// ---- same but fp32 source (used for W) ----
__global__ void k_shuf_f32(const float* __restrict__ in, _Float16* __restrict__ out) {
    size_t g = (size_t)blockIdx.x * 256 + threadIdx.x;
    int rt = (int)(g >> 10), ks = (int)(g >> 6) & 15, l = (int)g & 63;
    const float* src = in + ((size_t)(rt * 16 + (l & 15))) * 512 + ks * 32 + (l >> 4) * 8;
    float4 v0 = *(const float4*)src;
    float4 v1 = *(const float4*)(src + 4);
    f16x8 h = {(_Float16)v0.x, (_Float16)v0.y, (_Float16)v0.z, (_Float16)v0.w,
               (_Float16)v1.x, (_Float16)v1.y, (_Float16)v1.z, (_Float16)v1.w};
    *(f16x8*)(out + g * 8) = h;
}

// ---- prep: qT[b][d][j] = fp16(q[b][j][d]) (row-major; shuffled afterwards) ----
__global__ void k_prep_qt(const float* __restrict__ q, _Float16* __restrict__ qT) {
    __shared__ _Float16 t[64][65];
    int b  = blockIdx.x;
    int jt = blockIdx.y;            // QL/64
    int dt = blockIdx.z;            // DIM/64
    const float* src = q + ((size_t)b * QL + jt * 64) * DIM + dt * 64;
    int r0 = threadIdx.x >> 6;
    int cc = threadIdx.x & 63;
#pragma unroll
    for (int p = 0; p < 16; ++p) {
        int r = r0 + p * 4;
        t[r][cc] = (_Float16)src[(size_t)r * DIM + cc];
    }
    __syncthreads();
    _Float16* dst = qT + ((size_t)b * DIM + dt * 64) * QL + jt * 64;
#pragma unroll
    for (int p = 0; p < 16; ++p) {
        int r = r0 + p * 4;
        dst[(size_t)r * QL + cc] = t[cc][r];
    }
}

// ---- Y = relu(X @ W^T + b) fp16, 128x128 tiles, K=512, B from shuffled WhS ----
__global__ __launch_bounds__(256)
__attribute__((amdgpu_waves_per_eu(3)))
void k_proj(const float* __restrict__ X, const _Float16* __restrict__ WhS,
            const float* __restrict__ bias, _Float16* __restrict__ Y) {
    __shared__ __align__(16) _Float16 Ah[128 * LDP];
    int m0 = blockIdx.x * 128;
    int n0 = blockIdx.y * 128;
    int tid = threadIdx.x;
    int w = tid >> 6, lane = tid & 63;
    int col = lane & 15, quad = lane >> 4;
    int wm = (w >> 1) * 64, wn = (w & 1) * 64;
    int et0 = (n0 + wn) >> 4;

    f32x4 acc[4][4];
#pragma unroll
    for (int it = 0; it < 4; ++it)
#pragma unroll
        for (int jt = 0; jt < 4; ++jt) acc[it][jt] = (f32x4){0.f, 0.f, 0.f, 0.f};

    for (int kc = 0; kc < 8; ++kc) {       // BK=64
        // stage A: 128 rows x 64 floats -> fp16 (2048 float4, 8/thread)
#pragma unroll
        for (int p = 0; p < 8; ++p) {
            int s = tid + p * 256;
            int r = s >> 4, c4 = (s & 15) * 4;
            float4 v = *(const float4*)(X + (size_t)(m0 + r) * DIM + kc * 64 + c4);
            f16x4 h = {(_Float16)v.x, (_Float16)v.y, (_Float16)v.z, (_Float16)v.w};
            *(f16x4*)&Ah[r * LDP + c4] = h;
        }
        __syncthreads();
#pragma unroll
        for (int kc2 = 0; kc2 < 2; ++kc2) {
            int ks = kc * 2 + kc2;
            f16x8 af[4], bf[4];
#pragma unroll
            for (int it = 0; it < 4; ++it)
                af[it] = *(const f16x8*)&Ah[(wm + it * 16 + col) * LDP + kc2 * 32 + quad * 8];
#pragma unroll
            for (int jt = 0; jt < 4; ++jt)
                bf[jt] = *(const f16x8*)(WhS + (((size_t)(et0 + jt) * 16 + ks) * 64 + lane) * 8);
#pragma unroll
            for (int it = 0; it < 4; ++it)
#pragma unroll
                for (int jt = 0; jt < 4; ++jt)
                    acc[it][jt] = __builtin_amdgcn_mfma_f32_16x16x32_f16(af[it], bf[jt], acc[it][jt], 0, 0, 0);
        }
        __syncthreads();
    }
    // epilogue: bias + relu -> fp16 row-major
#pragma unroll
    for (int jt = 0; jt < 4; ++jt) {
        int e = n0 + wn + jt * 16 + col;
        float bv = bias[e];
#pragma unroll
        for (int it = 0; it < 4; ++it)
#pragma unroll
            for (int r = 0; r < 4; ++r) {
                int row = m0 + wm + it * 16 + quad * 4 + r;
                Y[(size_t)row * DIM + e] = (_Float16)fmaxf(acc[it][jt][r] + bv, 0.f);
            }
    }
}

// ---- fused attention: scores -> softmax -> mix ; B operands fragment-major ----
__global__ __launch_bounds__(256)
__attribute__((amdgpu_waves_per_eu(3)))
void k_attn(const _Float16* __restrict__ cf, const _Float16* __restrict__ qfS,
            const _Float16* __restrict__ qTS, float* __restrict__ out) {
    __shared__ __align__(16) _Float16 At[CT][LDA];   // cf tile, then attn tile
    __shared__ float redmax[4][32];
    __shared__ float redsum[4][32];

    int b   = blockIdx.x >> 6;            // 32 batches
    int c0  = (blockIdx.x & 63) * CT;     // 64 c-tiles of 32
    int tid = threadIdx.x;
    int w = tid >> 6, lane = tid & 63;
    int col = lane & 15, quad = lane >> 4;
    int obase = w * 128;                  // this wave's j / d column range
    int rt0 = b * 32 + w * 8;             // fragment row-tile base for this wave

    // ---- stage cf tile (fp16, contiguous) ----
    const _Float16* cfb = cf + ((size_t)b * CL + c0) * DIM;
#pragma unroll
    for (int p = 0; p < 8; ++p) {
        int s = tid + p * 256;
        int r = s >> 6, cc = s & 63;
        *(uint4*)&At[r][cc * 8] = *(const uint4*)(cfb + (size_t)r * DIM + cc * 8);
    }
    __syncthreads();

    // ---- phase 2: S = cf_tile @ qf^T ; B fragments contiguous from qfS ----
    f32x4 acc[2][8];
#pragma unroll
    for (int it = 0; it < 2; ++it)
#pragma unroll
        for (int jt = 0; jt < 8; ++jt) acc[it][jt] = (f32x4){0.f, 0.f, 0.f, 0.f};
#pragma unroll 4
    for (int kc = 0; kc < 16; ++kc) {
        int k0 = kc * 32;
        f16x8 bf[8];
#pragma unroll
        for (int jt = 0; jt < 8; ++jt)
            bf[jt] = *(const f16x8*)(qfS + (((size_t)(rt0 + jt) * 16 + kc) * 64 + lane) * 8);
        f16x8 a0 = *(const f16x8*)&At[col][k0 + quad * 8];
        f16x8 a1 = *(const f16x8*)&At[16 + col][k0 + quad * 8];
#pragma unroll
        for (int jt = 0; jt < 8; ++jt) {
            acc[0][jt] = __builtin_amdgcn_mfma_f32_16x16x32_f16(a0, bf[jt], acc[0][jt], 0, 0, 0);
            acc[1][jt] = __builtin_amdgcn_mfma_f32_16x16x32_f16(a1, bf[jt], acc[1][jt], 0, 0, 0);
        }
    }

    // ---- phase 3: softmax over j ----
    float sm[2][4];
#pragma unroll
    for (int it = 0; it < 2; ++it)
#pragma unroll
        for (int r = 0; r < 4; ++r) {
            float m = -1e30f;
#pragma unroll
            for (int jt = 0; jt < 8; ++jt) m = fmaxf(m, acc[it][jt][r]);
            m = fmaxf(m, __shfl_xor(m, 1));
            m = fmaxf(m, __shfl_xor(m, 2));
            m = fmaxf(m, __shfl_xor(m, 4));
            m = fmaxf(m, __shfl_xor(m, 8));
            sm[it][r] = m;
        }
    if (col == 0) {
#pragma unroll
        for (int it = 0; it < 2; ++it)
#pragma unroll
            for (int r = 0; r < 4; ++r) redmax[w][it * 16 + quad * 4 + r] = sm[it][r];
    }
    __syncthreads();   // also covers all At(cf) reads
#pragma unroll
    for (int it = 0; it < 2; ++it)
#pragma unroll
        for (int r = 0; r < 4; ++r) {
            int i = it * 16 + quad * 4 + r;
            float gm = fmaxf(fmaxf(redmax[0][i], redmax[1][i]),
                             fmaxf(redmax[2][i], redmax[3][i]));
            float s = 0.f;
#pragma unroll
            for (int jt = 0; jt < 8; ++jt) {
                float e = __expf(acc[it][jt][r] - gm);
                acc[it][jt][r] = e;
                s += e;
            }
            s += __shfl_xor(s, 1);
            s += __shfl_xor(s, 2);
            s += __shfl_xor(s, 4);
            s += __shfl_xor(s, 8);
            sm[it][r] = s;
        }
    if (col == 0) {
#pragma unroll
        for (int it = 0; it < 2; ++it)
#pragma unroll
            for (int r = 0; r < 4; ++r) redsum[w][it * 16 + quad * 4 + r] = sm[it][r];
    }
    __syncthreads();
#pragma unroll
    for (int it = 0; it < 2; ++it)
#pragma unroll
        for (int r = 0; r < 4; ++r) {
            int i = it * 16 + quad * 4 + r;
            float tot = redsum[0][i] + redsum[1][i] + redsum[2][i] + redsum[3][i];
            float inv = 1.f / tot;
#pragma unroll
            for (int jt = 0; jt < 8; ++jt)
                At[i][obase + jt * 16 + col] = (_Float16)(acc[it][jt][r] * inv);
        }
    __syncthreads();   // attn tile visible to all waves

    // ---- phase 4: mix = attn @ q ; B fragments contiguous from qTS ----
#pragma unroll
    for (int it = 0; it < 2; ++it)
#pragma unroll
        for (int jt = 0; jt < 8; ++jt) acc[it][jt] = (f32x4){0.f, 0.f, 0.f, 0.f};
#pragma unroll 4
    for (int kc = 0; kc < 16; ++kc) {
        int k0 = kc * 32;
        f16x8 bf[8];
#pragma unroll
        for (int dt = 0; dt < 8; ++dt)
            bf[dt] = *(const f16x8*)(qTS + (((size_t)(rt0 + dt) * 16 + kc) * 64 + lane) * 8);
        f16x8 a0 = *(const f16x8*)&At[col][k0 + quad * 8];
        f16x8 a1 = *(const f16x8*)&At[16 + col][k0 + quad * 8];
#pragma unroll
        for (int dt = 0; dt < 8; ++dt) {
            acc[0][dt] = __builtin_amdgcn_mfma_f32_16x16x32_f16(a0, bf[dt], acc[0][dt], 0, 0, 0);
            acc[1][dt] = __builtin_amdgcn_mfma_f32_16x16x32_f16(a1, bf[dt], acc[1][dt], 0, 0, 0);
        }
    }
    // ---- epilogue: out fp32 ----
#pragma unroll
    for (int dt = 0; dt < 8; ++dt) {
        int d = obase + dt * 16 + col;
#pragma unroll
        for (int it = 0; it < 2; ++it)
#pragma unroll
            for (int r = 0; r < 4; ++r) {
                int i = it * 16 + quad * 4 + r;
                out[((size_t)b * CL + c0 + i) * DIM + d] = acc[it][dt][r];
            }
    }
}

extern "C" void kernel_launch(void* const* d_in, const int* in_sizes, int n_in,
                              void* d_out, int out_size, void* d_ws, size_t ws_size,
                              hipStream_t stream) {
    const float* c    = (const float*)d_in[0];
    const float* q    = (const float*)d_in[1];
    const float* W    = (const float*)d_in[2];
    const float* bias = (const float*)d_in[3];
    float* out = (float*)d_out;

    // ws: WhS 512K | qfS 16M | qTS 16M | scratch 64M (qf tmp, qT tmp, then cf)
    char* ws = (char*)d_ws;
    _Float16* WhS = (_Float16*)ws;                                  // 512 KB
    _Float16* qfS = (_Float16*)(ws + 524288);                       // 16 MB
    _Float16* qTS = (_Float16*)(ws + 524288 + 16777216);            // 16 MB
    char* scratch = ws + 524288 + 2 * 16777216;                     // 64 MB
    _Float16* qf = (_Float16*)scratch;                              // 16 MB (temp)
    _Float16* qT = (_Float16*)(scratch + 16777216);                 // 16 MB (temp)
    _Float16* cf = (_Float16*)scratch;                              // 64 MB (after temps die)

    k_shuf_f32<<<128, 256, 0, stream>>>(W, WhS);                         // W -> WhS
    k_proj<<<dim3(BATCH * QL / 128, 4), 256, 0, stream>>>(q, WhS, bias, qf);
    k_shuf_f16<<<4096, 256, 0, stream>>>(qf, qfS);                       // qf -> qfS
    k_prep_qt<<<dim3(BATCH, QL / 64, DIM / 64), 256, 0, stream>>>(q, qT);
    k_shuf_f16<<<4096, 256, 0, stream>>>(qT, qTS);                       // qT -> qTS
    k_proj<<<dim3(BATCH * CL / 128, 4), 256, 0, stream>>>(c, WhS, bias, cf);
    k_attn<<<BATCH * (CL / CT), 256, 0, stream>>>(cf, qfS, qTS, out);
}